// Round 1
// baseline (63.615 us; speedup 1.0000x reference)
//
#include <hip/hip_runtime.h>
#include <hip/hip_bf16.h>
#include <stdint.h>

typedef int v4i __attribute__((ext_vector_type(4)));

#define M_TOK 2048
#define NFEAT 2048
#define KDIM  2048

// ---------------- init: zero the two absmax slots ----------------
__global__ void k_init(unsigned* slots) {
  if (threadIdx.x < 2) slots[threadIdx.x] = 0u;
}

// ---------------- absmax over x (y=0) and w (y=1) ----------------
__global__ void k_absmax(const float4* __restrict__ x, const float4* __restrict__ w,
                         unsigned* __restrict__ slots) {
  const float4* src = blockIdx.y ? w : x;
  const int n4 = (M_TOK * KDIM) / 4;
  float m = 0.0f;
  for (int i = blockIdx.x * blockDim.x + threadIdx.x; i < n4; i += gridDim.x * blockDim.x) {
    float4 v = src[i];
    m = fmaxf(m, fmaxf(fmaxf(fabsf(v.x), fabsf(v.y)), fmaxf(fabsf(v.z), fabsf(v.w))));
  }
  #pragma unroll
  for (int o = 32; o > 0; o >>= 1) m = fmaxf(m, __shfl_down(m, o, 64));
  __shared__ float sm[4];
  const int wid = threadIdx.x >> 6, lane = threadIdx.x & 63;
  if (lane == 0) sm[wid] = m;
  __syncthreads();
  if (threadIdx.x == 0) {
    float bm = fmaxf(fmaxf(sm[0], sm[1]), fmaxf(sm[2], sm[3]));
    atomicMax(slots + blockIdx.y, __float_as_uint(bm));
  }
}

// ---------------- quantize to int8 (bit-exact vs numpy) ----------------
__global__ void k_quant(const float4* __restrict__ x, const float4* __restrict__ w,
                        char4* __restrict__ qx, char4* __restrict__ qw,
                        const unsigned* __restrict__ slots) {
  const int which = blockIdx.y;
  const float4* src = which ? w : x;
  char4* dst = which ? qw : qx;
  const float s = __uint_as_float(slots[which]) / 127.0f;  // IEEE div, matches np
  const int i = blockIdx.x * blockDim.x + threadIdx.x;
  float4 v = src[i];
  float a = fminf(127.0f, fmaxf(-127.0f, rintf(v.x / s)));
  float b = fminf(127.0f, fmaxf(-127.0f, rintf(v.y / s)));
  float c = fminf(127.0f, fmaxf(-127.0f, rintf(v.z / s)));
  float d = fminf(127.0f, fmaxf(-127.0f, rintf(v.w / s)));
  char4 q;
  q.x = (signed char)(int)a; q.y = (signed char)(int)b;
  q.z = (signed char)(int)c; q.w = (signed char)(int)d;
  dst[i] = q;
}

// ---------------- int8 GEMM: C[m][n] = sum_k qx[m][k]*qw[n][k] ----------------
__device__ __forceinline__ void gload16(const void* g, void* l) {
  __builtin_amdgcn_global_load_lds(
      (const __attribute__((address_space(1))) uint32_t*)(uintptr_t)g,
      (__attribute__((address_space(3))) uint32_t*)(uint32_t)(uintptr_t)l,
      16, 0, 0);
}

__global__ __launch_bounds__(256) void k_gemm(const signed char* __restrict__ qa,
                                              const signed char* __restrict__ qb,
                                              const float* __restrict__ bias,
                                              const unsigned* __restrict__ slots,
                                              float* __restrict__ out) {
  // LDS tile layout: [kgroup(4)][row(128)][16 bytes]  (chunk c: kg=c>>7, row=c&127)
  __shared__ __align__(16) signed char lds[2][2][128 * 64];
  const int tid = threadIdx.x;
  const int lane = tid & 63, wid = tid >> 6;
  const int bid = blockIdx.x;
  const int tm = (bid >> 4) * 128, tn = (bid & 15) * 128;

  const int wm = (wid >> 1) * 64, wn = (wid & 1) * 64;
  const int kg = lane >> 4, lr = lane & 15;
  const int offA0 = kg * 2048 + (wm + lr) * 16;
  const int offB0 = kg * 2048 + (wn + lr) * 16;

  v4i acc[4][4] = {};

  auto stage = [&](int buf, int kt) {
    const int k0 = kt * 64;
    #pragma unroll
    for (int i = 0; i < 2; ++i) {
      const int c = i * 256 + wid * 64 + lane;
      const int row = c & 127, ckg = c >> 7;
      const int ldsoff = (i * 256 + wid * 64) * 16;  // wave-uniform base; HW adds lane*16
      gload16(qa + (size_t)(tm + row) * KDIM + k0 + ckg * 16, &lds[buf][0][ldsoff]);
      gload16(qb + (size_t)(tn + row) * KDIM + k0 + ckg * 16, &lds[buf][1][ldsoff]);
    }
  };

  stage(0, 0);
  asm volatile("s_waitcnt vmcnt(0)" ::: "memory");
  __syncthreads();

  const int NKT = KDIM / 64;
  for (int kt = 0; kt < NKT; ++kt) {
    const int cur = kt & 1;
    if (kt + 1 < NKT) stage(cur ^ 1, kt + 1);
    v4i af[4], bf[4];
    #pragma unroll
    for (int mi = 0; mi < 4; ++mi) af[mi] = *(const v4i*)&lds[cur][0][offA0 + mi * 256];
    #pragma unroll
    for (int ni = 0; ni < 4; ++ni) bf[ni] = *(const v4i*)&lds[cur][1][offB0 + ni * 256];
    #pragma unroll
    for (int mi = 0; mi < 4; ++mi)
      #pragma unroll
      for (int ni = 0; ni < 4; ++ni)
        acc[mi][ni] = __builtin_amdgcn_mfma_i32_16x16x64_i8(af[mi], bf[ni], acc[mi][ni], 0, 0, 0);
    asm volatile("s_waitcnt vmcnt(0)" ::: "memory");
    __syncthreads();
  }

  const float sx = __uint_as_float(slots[0]) / 127.0f;
  const float sw = __uint_as_float(slots[1]) / 127.0f;
  const float deq = sx * sw;
  #pragma unroll
  for (int ni = 0; ni < 4; ++ni) {
    const int col = tn + wn + ni * 16 + lr;
    const float bv = bias[col];
    #pragma unroll
    for (int mi = 0; mi < 4; ++mi) {
      const int row0 = tm + wm + mi * 16 + kg * 4;
      #pragma unroll
      for (int r = 0; r < 4; ++r)
        out[(size_t)(row0 + r) * NFEAT + col] = (float)acc[mi][ni][r] * deq + bv;
    }
  }
}

extern "C" void kernel_launch(void* const* d_in, const int* in_sizes, int n_in,
                              void* d_out, int out_size, void* d_ws, size_t ws_size,
                              hipStream_t stream) {
  const float* x    = (const float*)d_in[0];
  const float* w    = (const float*)d_in[1];
  const float* bias = (const float*)d_in[2];
  float* out = (float*)d_out;

  unsigned* slots = (unsigned*)d_ws;
  signed char* qx = (signed char*)d_ws + 256;
  signed char* qw = qx + (size_t)M_TOK * KDIM;

  k_init<<<1, 64, 0, stream>>>(slots);
  k_absmax<<<dim3(512, 2), 256, 0, stream>>>((const float4*)x, (const float4*)w, slots);
  k_quant<<<dim3((M_TOK * KDIM / 4) / 256, 2), 256, 0, stream>>>(
      (const float4*)x, (const float4*)w, (char4*)qx, (char4*)qw, slots);
  k_gemm<<<dim3(256), 256, 0, stream>>>(qx, qw, bias, slots, out);
}

// Round 2
// 61.165 us; speedup vs baseline: 1.0401x; 1.0401x over previous
//
#include <hip/hip_runtime.h>
#include <hip/hip_bf16.h>
#include <stdint.h>

typedef int v4i __attribute__((ext_vector_type(4)));

#define M_TOK 2048
#define NFEAT 2048
#define KDIM  2048

// ---------------- init: zero the two absmax slots ----------------
__global__ void k_init(unsigned* slots) {
  if (threadIdx.x < 2) slots[threadIdx.x] = 0u;
}

// ---------------- absmax over x (y=0) and w (y=1) ----------------
__global__ void k_absmax(const float4* __restrict__ x, const float4* __restrict__ w,
                         unsigned* __restrict__ slots) {
  const float4* src = blockIdx.y ? w : x;
  const int n4 = (M_TOK * KDIM) / 4;
  float m = 0.0f;
  for (int i = blockIdx.x * blockDim.x + threadIdx.x; i < n4; i += gridDim.x * blockDim.x) {
    float4 v = src[i];
    m = fmaxf(m, fmaxf(fmaxf(fabsf(v.x), fabsf(v.y)), fmaxf(fabsf(v.z), fabsf(v.w))));
  }
  #pragma unroll
  for (int o = 32; o > 0; o >>= 1) m = fmaxf(m, __shfl_down(m, o, 64));
  __shared__ float sm[4];
  const int wid = threadIdx.x >> 6, lane = threadIdx.x & 63;
  if (lane == 0) sm[wid] = m;
  __syncthreads();
  if (threadIdx.x == 0) {
    float bm = fmaxf(fmaxf(sm[0], sm[1]), fmaxf(sm[2], sm[3]));
    atomicMax(slots + blockIdx.y, __float_as_uint(bm));
  }
}

// ---------------- quantize to int8 (bit-exact vs numpy) ----------------
__global__ void k_quant(const float4* __restrict__ x, const float4* __restrict__ w,
                        char4* __restrict__ qx, char4* __restrict__ qw,
                        const unsigned* __restrict__ slots) {
  const int which = blockIdx.y;
  const float4* src = which ? w : x;
  char4* dst = which ? qw : qx;
  const float s = __uint_as_float(slots[which]) / 127.0f;  // IEEE div, matches np
  const int i = blockIdx.x * blockDim.x + threadIdx.x;
  float4 v = src[i];
  float a = fminf(127.0f, fmaxf(-127.0f, rintf(v.x / s)));
  float b = fminf(127.0f, fmaxf(-127.0f, rintf(v.y / s)));
  float c = fminf(127.0f, fmaxf(-127.0f, rintf(v.z / s)));
  float d = fminf(127.0f, fmaxf(-127.0f, rintf(v.w / s)));
  char4 q;
  q.x = (signed char)(int)a; q.y = (signed char)(int)b;
  q.z = (signed char)(int)c; q.w = (signed char)(int)d;
  dst[i] = q;
}

// ---------------- int8 GEMM: C[m][n] = sum_k qx[m][k]*qw[n][k] ----------------
// Tile 128(M)x64(N), BK=64, 4 waves (2x2), wave tile 64x32 (4x2 frags 16x16x64).
// Grid 512 blocks -> 2 blocks/CU -> 2 waves/SIMD: cross-block stall hiding.
__device__ __forceinline__ void gload16(const void* g, void* l) {
  __builtin_amdgcn_global_load_lds(
      (const __attribute__((address_space(1))) uint32_t*)(uintptr_t)g,
      (__attribute__((address_space(3))) uint32_t*)(uint32_t)(uintptr_t)l,
      16, 0, 0);
}

__global__ __launch_bounds__(256, 2) void k_gemm(const signed char* __restrict__ qa,
                                                 const signed char* __restrict__ qb,
                                                 const float* __restrict__ bias,
                                                 const unsigned* __restrict__ slots,
                                                 float* __restrict__ out) {
  // LDS: A [4 kg][128 row][16B] = 8KB ; B [4 kg][64 row][16B] = 4KB ; x2 buffers
  __shared__ __align__(16) signed char ldsA[2][128 * 64];
  __shared__ __align__(16) signed char ldsB[2][64 * 64];
  const int tid = threadIdx.x;
  const int lane = tid & 63, wid = tid >> 6;
  const int bid = blockIdx.x;
  const int tm = (bid >> 5) * 128;   // 16 M-tiles
  const int tn = (bid & 31) * 64;    // 32 N-tiles

  const int wm = (wid >> 1) * 64, wn = (wid & 1) * 32;
  const int kg = lane >> 4, lr = lane & 15;
  const int offA0 = kg * 2048 + (wm + lr) * 16;
  const int offB0 = kg * 1024 + (wn + lr) * 16;

  v4i acc[4][2] = {};

  auto stage = [&](int buf, int kt) {
    const int k0 = kt * 64;
    #pragma unroll
    for (int i = 0; i < 2; ++i) {        // A: 512 chunks of 16B
      const int c = i * 256 + wid * 64 + lane;
      const int row = c & 127, ckg = c >> 7;
      const int ldsoff = (i * 256 + wid * 64) * 16;  // wave-uniform base; HW adds lane*16
      gload16(qa + (size_t)(tm + row) * KDIM + k0 + ckg * 16, &ldsA[buf][ldsoff]);
    }
    {                                    // B: 256 chunks of 16B
      const int c = wid * 64 + lane;
      const int row = c & 63, ckg = c >> 6;
      gload16(qb + (size_t)(tn + row) * KDIM + k0 + ckg * 16, &ldsB[buf][(wid * 64) * 16]);
    }
  };

  stage(0, 0);
  asm volatile("s_waitcnt vmcnt(0)" ::: "memory");
  __syncthreads();

  const int NKT = KDIM / 64;
  for (int kt = 0; kt < NKT; ++kt) {
    const int cur = kt & 1;
    if (kt + 1 < NKT) stage(cur ^ 1, kt + 1);
    v4i af[4], bf[2];
    #pragma unroll
    for (int mi = 0; mi < 4; ++mi) af[mi] = *(const v4i*)&ldsA[cur][offA0 + mi * 256];
    #pragma unroll
    for (int ni = 0; ni < 2; ++ni) bf[ni] = *(const v4i*)&ldsB[cur][offB0 + ni * 256];
    #pragma unroll
    for (int mi = 0; mi < 4; ++mi)
      #pragma unroll
      for (int ni = 0; ni < 2; ++ni)
        acc[mi][ni] = __builtin_amdgcn_mfma_i32_16x16x64_i8(af[mi], bf[ni], acc[mi][ni], 0, 0, 0);
    asm volatile("s_waitcnt vmcnt(0)" ::: "memory");
    __syncthreads();
  }

  const float sx = __uint_as_float(slots[0]) / 127.0f;
  const float sw = __uint_as_float(slots[1]) / 127.0f;
  const float deq = sx * sw;
  #pragma unroll
  for (int ni = 0; ni < 2; ++ni) {
    const int col = tn + wn + ni * 16 + lr;
    const float bv = bias[col];
    #pragma unroll
    for (int mi = 0; mi < 4; ++mi) {
      const int row0 = tm + wm + mi * 16 + kg * 4;
      #pragma unroll
      for (int r = 0; r < 4; ++r)
        out[(size_t)(row0 + r) * NFEAT + col] = (float)acc[mi][ni][r] * deq + bv;
    }
  }
}

extern "C" void kernel_launch(void* const* d_in, const int* in_sizes, int n_in,
                              void* d_out, int out_size, void* d_ws, size_t ws_size,
                              hipStream_t stream) {
  const float* x    = (const float*)d_in[0];
  const float* w    = (const float*)d_in[1];
  const float* bias = (const float*)d_in[2];
  float* out = (float*)d_out;

  unsigned* slots = (unsigned*)d_ws;
  signed char* qx = (signed char*)d_ws + 256;
  signed char* qw = qx + (size_t)M_TOK * KDIM;

  k_init<<<1, 64, 0, stream>>>(slots);
  k_absmax<<<dim3(512, 2), 256, 0, stream>>>((const float4*)x, (const float4*)w, slots);
  k_quant<<<dim3((M_TOK * KDIM / 4) / 256, 2), 256, 0, stream>>>(
      (const float4*)x, (const float4*)w, (char4*)qx, (char4*)qw, slots);
  k_gemm<<<dim3(512), 256, 0, stream>>>(qx, qw, bias, slots, out);
}